// Round 2
// baseline (5144.811 us; speedup 1.0000x reference)
//
#include <hip/hip_runtime.h>

constexpr int ED = 64;    // edge feature dim
constexpr int ND = 128;   // node feature dim

// Pre-transpose W[64][128] into paired layout: Wp[k*64+j] = {W[k][j], W[k][j+64]}
// so one dwordx2 load per lane serves both output columns.
__global__ void prep_w_kernel(const float* __restrict__ W, float2* __restrict__ Wp)
{
    const int t = blockIdx.x * blockDim.x + threadIdx.x;
    if (t < ED * 64) {
        const int k = t >> 6, j = t & 63;
        Wp[t] = make_float2(W[k * ND + j], W[k * ND + 64 + j]);
    }
}

// One wave processes FOUR edges per iteration. Lane j owns output cols j and
// j+64 for all four edges. The four FMA chains are independent (8-way ILP),
// W is fetched once per k per 4 edges, and all 16 feature atomics are issued
// back-to-back so the vmcnt drain is amortized 4x.
__global__ __launch_bounds__(256, 4)
void edge_scatter_kernel(const float* __restrict__ x,
                         const float2* __restrict__ Wp,
                         const float* __restrict__ bias,
                         const float* __restrict__ gamma,
                         const float* __restrict__ beta,
                         const int*   __restrict__ ei,
                         int E,
                         float* __restrict__ out,
                         float* __restrict__ deg)
{
    const int lane = threadIdx.x & 63;
    const int wid  = blockIdx.x * (blockDim.x >> 6) + (threadIdx.x >> 6);
    const int nw   = gridDim.x * (blockDim.x >> 6);

    const float b0 = bias[lane],  b1 = bias[lane + 64];
    const float g0 = gamma[lane], g1 = gamma[lane + 64];
    const float p0 = beta[lane],  p1 = beta[lane + 64];

    const int ngroups = E >> 2;

    for (int g = wid; g < ngroups; g += nw) {
        const int e0 = g << 2;

        const int xi0 = __float_as_int(x[(size_t)(e0 + 0) * ED + lane]);
        const int xi1 = __float_as_int(x[(size_t)(e0 + 1) * ED + lane]);
        const int xi2 = __float_as_int(x[(size_t)(e0 + 2) * ED + lane]);
        const int xi3 = __float_as_int(x[(size_t)(e0 + 3) * ED + lane]);

        float h00 = b0, h01 = b1, h10 = b0, h11 = b1;
        float h20 = b0, h21 = b1, h30 = b0, h31 = b1;
#pragma unroll
        for (int k = 0; k < ED; ++k) {
            const float2 w = Wp[k * 64 + lane];
            const float x0 = __int_as_float(__builtin_amdgcn_readlane(xi0, k));
            const float x1 = __int_as_float(__builtin_amdgcn_readlane(xi1, k));
            const float x2 = __int_as_float(__builtin_amdgcn_readlane(xi2, k));
            const float x3 = __int_as_float(__builtin_amdgcn_readlane(xi3, k));
            h00 = fmaf(x0, w.x, h00); h01 = fmaf(x0, w.y, h01);
            h10 = fmaf(x1, w.x, h10); h11 = fmaf(x1, w.y, h11);
            h20 = fmaf(x2, w.x, h20); h21 = fmaf(x2, w.y, h21);
            h30 = fmaf(x3, w.x, h30); h31 = fmaf(x3, w.y, h31);
        }
        // ReLU
        h00 = fmaxf(h00, 0.f); h01 = fmaxf(h01, 0.f);
        h10 = fmaxf(h10, 0.f); h11 = fmaxf(h11, 0.f);
        h20 = fmaxf(h20, 0.f); h21 = fmaxf(h21, 0.f);
        h30 = fmaxf(h30, 0.f); h31 = fmaxf(h31, 0.f);

        // LayerNorm: wave-wide sum/sumsq for 4 edges simultaneously
        float s0 = h00 + h01, q0 = fmaf(h00, h00, h01 * h01);
        float s1 = h10 + h11, q1 = fmaf(h10, h10, h11 * h11);
        float s2 = h20 + h21, q2 = fmaf(h20, h20, h21 * h21);
        float s3 = h30 + h31, q3 = fmaf(h30, h30, h31 * h31);
#pragma unroll
        for (int m = 1; m < 64; m <<= 1) {
            s0 += __shfl_xor(s0, m, 64); q0 += __shfl_xor(q0, m, 64);
            s1 += __shfl_xor(s1, m, 64); q1 += __shfl_xor(q1, m, 64);
            s2 += __shfl_xor(s2, m, 64); q2 += __shfl_xor(q2, m, 64);
            s3 += __shfl_xor(s3, m, 64); q3 += __shfl_xor(q3, m, 64);
        }
        const float inv = 1.0f / ND;
        const float mu0 = s0 * inv, rs0 = rsqrtf(q0 * inv - mu0 * mu0 + 1e-5f);
        const float mu1 = s1 * inv, rs1 = rsqrtf(q1 * inv - mu1 * mu1 + 1e-5f);
        const float mu2 = s2 * inv, rs2 = rsqrtf(q2 * inv - mu2 * mu2 + 1e-5f);
        const float mu3 = s3 * inv, rs3 = rsqrtf(q3 * inv - mu3 * mu3 + 1e-5f);

        const float y00 = (h00 - mu0) * rs0 * g0 + p0, y01 = (h01 - mu0) * rs0 * g1 + p1;
        const float y10 = (h10 - mu1) * rs1 * g0 + p0, y11 = (h11 - mu1) * rs1 * g1 + p1;
        const float y20 = (h20 - mu2) * rs2 * g0 + p0, y21 = (h21 - mu2) * rs2 * g1 + p1;
        const float y30 = (h30 - mu3) * rs3 * g0 + p0, y31 = (h31 - mu3) * rs3 * g1 + p1;

        const int sn0 = ei[e0 + 0], dn0 = ei[E + e0 + 0];
        const int sn1 = ei[e0 + 1], dn1 = ei[E + e0 + 1];
        const int sn2 = ei[e0 + 2], dn2 = ei[E + e0 + 2];
        const int sn3 = ei[e0 + 3], dn3 = ei[E + e0 + 3];

        // 16 feature atomics issued back-to-back (single drain point)
        unsafeAtomicAdd(&out[(size_t)dn0 * ND + lane],      y00);
        unsafeAtomicAdd(&out[(size_t)dn0 * ND + 64 + lane], y01);
        unsafeAtomicAdd(&out[(size_t)sn0 * ND + lane],      y00);
        unsafeAtomicAdd(&out[(size_t)sn0 * ND + 64 + lane], y01);
        unsafeAtomicAdd(&out[(size_t)dn1 * ND + lane],      y10);
        unsafeAtomicAdd(&out[(size_t)dn1 * ND + 64 + lane], y11);
        unsafeAtomicAdd(&out[(size_t)sn1 * ND + lane],      y10);
        unsafeAtomicAdd(&out[(size_t)sn1 * ND + 64 + lane], y11);
        unsafeAtomicAdd(&out[(size_t)dn2 * ND + lane],      y20);
        unsafeAtomicAdd(&out[(size_t)dn2 * ND + 64 + lane], y21);
        unsafeAtomicAdd(&out[(size_t)sn2 * ND + lane],      y20);
        unsafeAtomicAdd(&out[(size_t)sn2 * ND + 64 + lane], y21);
        unsafeAtomicAdd(&out[(size_t)dn3 * ND + lane],      y30);
        unsafeAtomicAdd(&out[(size_t)dn3 * ND + 64 + lane], y31);
        unsafeAtomicAdd(&out[(size_t)sn3 * ND + lane],      y30);
        unsafeAtomicAdd(&out[(size_t)sn3 * ND + 64 + lane], y31);

        // degree increments: ONE atomic instruction, 8 active lanes
        int nid = dn0;
        if (lane == 1) nid = dn1;
        if (lane == 2) nid = dn2;
        if (lane == 3) nid = dn3;
        if (lane == 4) nid = sn0;
        if (lane == 5) nid = sn1;
        if (lane == 6) nid = sn2;
        if (lane == 7) nid = sn3;
        if (lane < 8) unsafeAtomicAdd(&deg[nid], 1.0f);
    }

    // tail (E not divisible by 4): single-edge path
    for (int e = (ngroups << 2) + wid; e < E; e += nw) {
        const int xi = __float_as_int(x[(size_t)e * ED + lane]);
        float h0 = b0, h1 = b1;
#pragma unroll
        for (int k = 0; k < ED; ++k) {
            const float2 w = Wp[k * 64 + lane];
            const float xk = __int_as_float(__builtin_amdgcn_readlane(xi, k));
            h0 = fmaf(xk, w.x, h0); h1 = fmaf(xk, w.y, h1);
        }
        h0 = fmaxf(h0, 0.f); h1 = fmaxf(h1, 0.f);
        float s = h0 + h1, q = fmaf(h0, h0, h1 * h1);
#pragma unroll
        for (int m = 1; m < 64; m <<= 1) {
            s += __shfl_xor(s, m, 64); q += __shfl_xor(q, m, 64);
        }
        const float mu = s / ND, rs = rsqrtf(q / ND - mu * mu + 1e-5f);
        const float y0 = (h0 - mu) * rs * g0 + p0, y1 = (h1 - mu) * rs * g1 + p1;
        const int sn = ei[e], dn = ei[E + e];
        unsafeAtomicAdd(&out[(size_t)dn * ND + lane],      y0);
        unsafeAtomicAdd(&out[(size_t)dn * ND + 64 + lane], y1);
        unsafeAtomicAdd(&out[(size_t)sn * ND + lane],      y0);
        unsafeAtomicAdd(&out[(size_t)sn * ND + 64 + lane], y1);
        if (lane == 0) unsafeAtomicAdd(&deg[dn], 1.0f);
        if (lane == 1) unsafeAtomicAdd(&deg[sn], 1.0f);
    }
}

__global__ void finalize_kernel(float4* __restrict__ out,
                                const float* __restrict__ deg,
                                int n4)
{
    const int i = blockIdx.x * blockDim.x + threadIdx.x;
    if (i < n4) {
        const float d = fmaxf(deg[i >> 5], 1.0f);   // 32 float4 per node row
        float4 v = out[i];
        v.x /= d; v.y /= d; v.z /= d; v.w /= d;
        out[i] = v;
    }
}

extern "C" void kernel_launch(void* const* d_in, const int* in_sizes, int n_in,
                              void* d_out, int out_size, void* d_ws, size_t ws_size,
                              hipStream_t stream)
{
    const float* x     = (const float*)d_in[0];
    const float* W     = (const float*)d_in[1];
    const float* bias  = (const float*)d_in[2];
    const float* gamma = (const float*)d_in[3];
    const float* beta  = (const float*)d_in[4];
    const int*   ei    = (const int*)d_in[5];

    const int E       = in_sizes[0] / ED;
    const int n_nodes = out_size / ND;

    float*  out = (float*)d_out;
    float*  deg = (float*)d_ws;                       // n_nodes floats
    float2* Wp  = (float2*)((char*)d_ws + (size_t)n_nodes * sizeof(float)); // 32 KB

    hipMemsetAsync(d_out, 0, (size_t)out_size * sizeof(float), stream);
    hipMemsetAsync(d_ws,  0, (size_t)n_nodes * sizeof(float), stream);

    prep_w_kernel<<<(ED * 64 + 255) / 256, 256, 0, stream>>>(W, Wp);

    edge_scatter_kernel<<<4096, 256, 0, stream>>>(x, Wp, bias, gamma, beta,
                                                  ei, E, out, deg);

    finalize_kernel<<<(out_size / 4 + 255) / 256, 256, 0, stream>>>(
        (float4*)out, deg, out_size / 4);
}

// Round 3
// 1893.607 us; speedup vs baseline: 2.7169x; 2.7169x over previous
//
#include <hip/hip_runtime.h>

constexpr int ED = 64;    // edge feature dim
constexpr int ND = 128;   // node feature dim

// One wave processes FOUR edges per iteration.
// W lives in LDS (loaded once per block): Wq[k2][j] is a float4 holding
//   {W[2k2][j], W[2k2][j+64], W[2k2+1][j], W[2k2+1][j+64]}
// so lane j serves output cols j and j+64 for two consecutive k with one
// ds_read_b128. The per-edge activation x is loaded as one dwordx4 per lane
// (lane j holds x[e0 + j/16][4*(j%16) .. +3]) and broadcast via v_readlane.
__global__ __launch_bounds__(256)
void edge_scatter_kernel(const float* __restrict__ x,
                         const float* __restrict__ W,
                         const float* __restrict__ bias,
                         const float* __restrict__ gamma,
                         const float* __restrict__ beta,
                         const int*   __restrict__ ei,
                         int E,
                         float* __restrict__ out,
                         float* __restrict__ deg)
{
    __shared__ float4 Wq[32 * 64];   // 32 KB

    // cooperative one-time load of W into LDS (paired-k, split-column layout)
    for (int t = threadIdx.x; t < 32 * 64; t += 256) {
        const int k2 = t >> 6, j = t & 63;
        const float* Wr = W + (size_t)(2 * k2) * ND;
        Wq[t] = make_float4(Wr[j], Wr[64 + j], Wr[ND + j], Wr[ND + 64 + j]);
    }
    __syncthreads();

    const int lane = threadIdx.x & 63;
    const int wid  = blockIdx.x * (blockDim.x >> 6) + (threadIdx.x >> 6);
    const int nw   = gridDim.x * (blockDim.x >> 6);

    const float b0 = bias[lane],  b1 = bias[lane + 64];
    const float g0 = gamma[lane], g1 = gamma[lane + 64];
    const float p0 = beta[lane],  p1 = beta[lane + 64];

    const int ngroups = E >> 2;
    const int4* x4 = (const int4*)x;

    for (int g = wid; g < ngroups; g += nw) {
        const int e0 = g << 2;

        // one dwordx4: lane j holds x[e0 + (j>>4)][4*(j&15) .. 4*(j&15)+3]
        const int4 xi = x4[(size_t)g * 64 + lane];

        float h00 = b0, h01 = b1, h10 = b0, h11 = b1;
        float h20 = b0, h21 = b1, h30 = b0, h31 = b1;

#pragma unroll
        for (int kq = 0; kq < 16; ++kq) {
            // k = 4*kq .. 4*kq+3
            const float4 wA = Wq[(2 * kq) * 64 + lane];      // k=4kq, 4kq+1
            const float4 wB = Wq[(2 * kq + 1) * 64 + lane];  // k=4kq+2, 4kq+3

            // edge 0
            {
                const int ls = 0 * 16 + kq;
                const float a0 = __int_as_float(__builtin_amdgcn_readlane(xi.x, ls));
                const float a1 = __int_as_float(__builtin_amdgcn_readlane(xi.y, ls));
                const float a2 = __int_as_float(__builtin_amdgcn_readlane(xi.z, ls));
                const float a3 = __int_as_float(__builtin_amdgcn_readlane(xi.w, ls));
                h00 = fmaf(a0, wA.x, h00); h01 = fmaf(a0, wA.y, h01);
                h00 = fmaf(a1, wA.z, h00); h01 = fmaf(a1, wA.w, h01);
                h00 = fmaf(a2, wB.x, h00); h01 = fmaf(a2, wB.y, h01);
                h00 = fmaf(a3, wB.z, h00); h01 = fmaf(a3, wB.w, h01);
            }
            // edge 1
            {
                const int ls = 1 * 16 + kq;
                const float a0 = __int_as_float(__builtin_amdgcn_readlane(xi.x, ls));
                const float a1 = __int_as_float(__builtin_amdgcn_readlane(xi.y, ls));
                const float a2 = __int_as_float(__builtin_amdgcn_readlane(xi.z, ls));
                const float a3 = __int_as_float(__builtin_amdgcn_readlane(xi.w, ls));
                h10 = fmaf(a0, wA.x, h10); h11 = fmaf(a0, wA.y, h11);
                h10 = fmaf(a1, wA.z, h10); h11 = fmaf(a1, wA.w, h11);
                h10 = fmaf(a2, wB.x, h10); h11 = fmaf(a2, wB.y, h11);
                h10 = fmaf(a3, wB.z, h10); h11 = fmaf(a3, wB.w, h11);
            }
            // edge 2
            {
                const int ls = 2 * 16 + kq;
                const float a0 = __int_as_float(__builtin_amdgcn_readlane(xi.x, ls));
                const float a1 = __int_as_float(__builtin_amdgcn_readlane(xi.y, ls));
                const float a2 = __int_as_float(__builtin_amdgcn_readlane(xi.z, ls));
                const float a3 = __int_as_float(__builtin_amdgcn_readlane(xi.w, ls));
                h20 = fmaf(a0, wA.x, h20); h21 = fmaf(a0, wA.y, h21);
                h20 = fmaf(a1, wA.z, h20); h21 = fmaf(a1, wA.w, h21);
                h20 = fmaf(a2, wB.x, h20); h21 = fmaf(a2, wB.y, h21);
                h20 = fmaf(a3, wB.z, h20); h21 = fmaf(a3, wB.w, h21);
            }
            // edge 3
            {
                const int ls = 3 * 16 + kq;
                const float a0 = __int_as_float(__builtin_amdgcn_readlane(xi.x, ls));
                const float a1 = __int_as_float(__builtin_amdgcn_readlane(xi.y, ls));
                const float a2 = __int_as_float(__builtin_amdgcn_readlane(xi.z, ls));
                const float a3 = __int_as_float(__builtin_amdgcn_readlane(xi.w, ls));
                h30 = fmaf(a0, wA.x, h30); h31 = fmaf(a0, wA.y, h31);
                h30 = fmaf(a1, wA.z, h30); h31 = fmaf(a1, wA.w, h31);
                h30 = fmaf(a2, wB.x, h30); h31 = fmaf(a2, wB.y, h31);
                h30 = fmaf(a3, wB.z, h30); h31 = fmaf(a3, wB.w, h31);
            }
        }

        // ReLU
        h00 = fmaxf(h00, 0.f); h01 = fmaxf(h01, 0.f);
        h10 = fmaxf(h10, 0.f); h11 = fmaxf(h11, 0.f);
        h20 = fmaxf(h20, 0.f); h21 = fmaxf(h21, 0.f);
        h30 = fmaxf(h30, 0.f); h31 = fmaxf(h31, 0.f);

        // LayerNorm: wave-wide sum/sumsq for 4 edges
        float s0 = h00 + h01, q0 = fmaf(h00, h00, h01 * h01);
        float s1 = h10 + h11, q1 = fmaf(h10, h10, h11 * h11);
        float s2 = h20 + h21, q2 = fmaf(h20, h20, h21 * h21);
        float s3 = h30 + h31, q3 = fmaf(h30, h30, h31 * h31);
#pragma unroll
        for (int m = 1; m < 64; m <<= 1) {
            s0 += __shfl_xor(s0, m, 64); q0 += __shfl_xor(q0, m, 64);
            s1 += __shfl_xor(s1, m, 64); q1 += __shfl_xor(q1, m, 64);
            s2 += __shfl_xor(s2, m, 64); q2 += __shfl_xor(q2, m, 64);
            s3 += __shfl_xor(s3, m, 64); q3 += __shfl_xor(q3, m, 64);
        }
        const float inv = 1.0f / ND;
        const float mu0 = s0 * inv, rs0 = rsqrtf(q0 * inv - mu0 * mu0 + 1e-5f);
        const float mu1 = s1 * inv, rs1 = rsqrtf(q1 * inv - mu1 * mu1 + 1e-5f);
        const float mu2 = s2 * inv, rs2 = rsqrtf(q2 * inv - mu2 * mu2 + 1e-5f);
        const float mu3 = s3 * inv, rs3 = rsqrtf(q3 * inv - mu3 * mu3 + 1e-5f);

        const float y00 = (h00 - mu0) * rs0 * g0 + p0, y01 = (h01 - mu0) * rs0 * g1 + p1;
        const float y10 = (h10 - mu1) * rs1 * g0 + p0, y11 = (h11 - mu1) * rs1 * g1 + p1;
        const float y20 = (h20 - mu2) * rs2 * g0 + p0, y21 = (h21 - mu2) * rs2 * g1 + p1;
        const float y30 = (h30 - mu3) * rs3 * g0 + p0, y31 = (h31 - mu3) * rs3 * g1 + p1;

        const int sn0 = ei[e0 + 0], dn0 = ei[E + e0 + 0];
        const int sn1 = ei[e0 + 1], dn1 = ei[E + e0 + 1];
        const int sn2 = ei[e0 + 2], dn2 = ei[E + e0 + 2];
        const int sn3 = ei[e0 + 3], dn3 = ei[E + e0 + 3];

        // 16 feature atomics issued back-to-back (single drain point)
        unsafeAtomicAdd(&out[(size_t)dn0 * ND + lane],      y00);
        unsafeAtomicAdd(&out[(size_t)dn0 * ND + 64 + lane], y01);
        unsafeAtomicAdd(&out[(size_t)sn0 * ND + lane],      y00);
        unsafeAtomicAdd(&out[(size_t)sn0 * ND + 64 + lane], y01);
        unsafeAtomicAdd(&out[(size_t)dn1 * ND + lane],      y10);
        unsafeAtomicAdd(&out[(size_t)dn1 * ND + 64 + lane], y11);
        unsafeAtomicAdd(&out[(size_t)sn1 * ND + lane],      y10);
        unsafeAtomicAdd(&out[(size_t)sn1 * ND + 64 + lane], y11);
        unsafeAtomicAdd(&out[(size_t)dn2 * ND + lane],      y20);
        unsafeAtomicAdd(&out[(size_t)dn2 * ND + 64 + lane], y21);
        unsafeAtomicAdd(&out[(size_t)sn2 * ND + lane],      y20);
        unsafeAtomicAdd(&out[(size_t)sn2 * ND + 64 + lane], y21);
        unsafeAtomicAdd(&out[(size_t)dn3 * ND + lane],      y30);
        unsafeAtomicAdd(&out[(size_t)dn3 * ND + 64 + lane], y31);
        unsafeAtomicAdd(&out[(size_t)sn3 * ND + lane],      y30);
        unsafeAtomicAdd(&out[(size_t)sn3 * ND + 64 + lane], y31);

        // degree increments: ONE atomic instruction, 8 active lanes
        int nid = dn0;
        if (lane == 1) nid = dn1;
        if (lane == 2) nid = dn2;
        if (lane == 3) nid = dn3;
        if (lane == 4) nid = sn0;
        if (lane == 5) nid = sn1;
        if (lane == 6) nid = sn2;
        if (lane == 7) nid = sn3;
        if (lane < 8) unsafeAtomicAdd(&deg[nid], 1.0f);
    }

    // tail (E not divisible by 4): single-edge path using LDS W
    for (int e = (ngroups << 2) + wid; e < E; e += nw) {
        const int xv = __float_as_int(x[(size_t)e * ED + lane]);
        float h0 = b0, h1 = b1;
#pragma unroll
        for (int kq = 0; kq < 16; ++kq) {
            const float4 wA = Wq[(2 * kq) * 64 + lane];
            const float4 wB = Wq[(2 * kq + 1) * 64 + lane];
            const float a0 = __int_as_float(__builtin_amdgcn_readlane(xv, 4 * kq + 0));
            const float a1 = __int_as_float(__builtin_amdgcn_readlane(xv, 4 * kq + 1));
            const float a2 = __int_as_float(__builtin_amdgcn_readlane(xv, 4 * kq + 2));
            const float a3 = __int_as_float(__builtin_amdgcn_readlane(xv, 4 * kq + 3));
            h0 = fmaf(a0, wA.x, h0); h1 = fmaf(a0, wA.y, h1);
            h0 = fmaf(a1, wA.z, h0); h1 = fmaf(a1, wA.w, h1);
            h0 = fmaf(a2, wB.x, h0); h1 = fmaf(a2, wB.y, h1);
            h0 = fmaf(a3, wB.z, h0); h1 = fmaf(a3, wB.w, h1);
        }
        h0 = fmaxf(h0, 0.f); h1 = fmaxf(h1, 0.f);
        float s = h0 + h1, q = fmaf(h0, h0, h1 * h1);
#pragma unroll
        for (int m = 1; m < 64; m <<= 1) {
            s += __shfl_xor(s, m, 64); q += __shfl_xor(q, m, 64);
        }
        const float mu = s / ND, rs = rsqrtf(q / ND - mu * mu + 1e-5f);
        const float y0 = (h0 - mu) * rs * g0 + p0, y1 = (h1 - mu) * rs * g1 + p1;
        const int sn = ei[e], dn = ei[E + e];
        unsafeAtomicAdd(&out[(size_t)dn * ND + lane],      y0);
        unsafeAtomicAdd(&out[(size_t)dn * ND + 64 + lane], y1);
        unsafeAtomicAdd(&out[(size_t)sn * ND + lane],      y0);
        unsafeAtomicAdd(&out[(size_t)sn * ND + 64 + lane], y1);
        if (lane == 0) unsafeAtomicAdd(&deg[dn], 1.0f);
        if (lane == 1) unsafeAtomicAdd(&deg[sn], 1.0f);
    }
}

__global__ void finalize_kernel(float4* __restrict__ out,
                                const float* __restrict__ deg,
                                int n4)
{
    const int i = blockIdx.x * blockDim.x + threadIdx.x;
    if (i < n4) {
        const float d = fmaxf(deg[i >> 5], 1.0f);   // 32 float4 per node row
        float4 v = out[i];
        v.x /= d; v.y /= d; v.z /= d; v.w /= d;
        out[i] = v;
    }
}

extern "C" void kernel_launch(void* const* d_in, const int* in_sizes, int n_in,
                              void* d_out, int out_size, void* d_ws, size_t ws_size,
                              hipStream_t stream)
{
    const float* x     = (const float*)d_in[0];
    const float* W     = (const float*)d_in[1];
    const float* bias  = (const float*)d_in[2];
    const float* gamma = (const float*)d_in[3];
    const float* beta  = (const float*)d_in[4];
    const int*   ei    = (const int*)d_in[5];

    const int E       = in_sizes[0] / ED;
    const int n_nodes = out_size / ND;

    float* out = (float*)d_out;
    float* deg = (float*)d_ws;

    hipMemsetAsync(d_out, 0, (size_t)out_size * sizeof(float), stream);
    hipMemsetAsync(d_ws,  0, (size_t)n_nodes * sizeof(float), stream);

    edge_scatter_kernel<<<4096, 256, 0, stream>>>(x, W, bias, gamma, beta,
                                                  ei, E, out, deg);

    finalize_kernel<<<(out_size / 4 + 255) / 256, 256, 0, stream>>>(
        (float4*)out, deg, out_size / 4);
}